// Round 7
// baseline (149.818 us; speedup 1.0000x reference)
//
#include <hip/hip_runtime.h>
#include <stdint.h>

#define BATCH 16
#define NQ 2000
#define NC 80
#define NG 100
#define MAX_ITERS 1000
#define MAXC 96
#define QT 64
#define TILES 32                     // ceil(2000/64)
#define K1_BLOCKS (BATCH * TILES)    // 512
#define K3_BS 1024
#define NW3 16
#define NCAND 12
#define LSTRIDE 13                   // k + 12 candidate indices
#define QINF 0x7fffffff

// output layout (floats)
#define OFF_SEL 0
#define OFF_GTI (BATCH * NQ)                 // 32000
#define OFF_MQ (2 * BATCH * NQ)              // 64000
#define OFF_M (2 * BATCH * NQ + BATCH * NG)  // 65600

// exact replay of the reference's sequential in-place +1e5 adds
__device__ __forceinline__ float fmut(float c, int k) {
    for (int i = 0; i < k; ++i) c += 100000.0f;
    return c;
}

__device__ __forceinline__ bool lexlt(float v1, int i1, float v2, int i2) {
    return (v1 < v2) | ((v1 == v2) & (i1 < i2));
}

// branchless compare-exchange ascending between slots a<b of (val,idx) arrays
#define CE(vv, ii, a, b) do { \
    bool t_ = lexlt(vv[b], ii[b], vv[a], ii[a]); \
    float lo_ = t_ ? vv[b] : vv[a]; float hi_ = t_ ? vv[a] : vv[b]; \
    int loi_ = t_ ? ii[b] : ii[a]; int hii_ = t_ ? ii[a] : ii[b]; \
    vv[a] = lo_; vv[b] = hi_; ii[a] = loi_; ii[b] = hii_; \
} while (0)

// =================== K1: fused fg + cost, tiled, transposed write ===================
__global__ __launch_bounds__(256) void fgcost_kernel(
    const float* __restrict__ logits, const float* __restrict__ pred_boxes,
    const float* __restrict__ gt_boxes, const int* __restrict__ labels,
    const float* __restrict__ img_sz, float* __restrict__ costT_all) {
    const int tid = threadIdx.x;
    const int b = blockIdx.x / TILES;
    const int tile = blockIdx.x - b * TILES;
    const int q0 = tile * QT;

    __shared__ float ct[QT][NG + 1];
    __shared__ float s_rx1[NG], s_ry1[NG], s_rx2[NG], s_ry2[NG];
    __shared__ float s_clx[NG], s_chx[NG], s_cly[NG], s_chy[NG];
    __shared__ float s_gx1[NG], s_gy1[NG], s_gx2[NG], s_gy2[NG];
    __shared__ float s_d1[NG], s_d2[NG], s_d3[NG], s_d4[NG];
    __shared__ float s_ga[NG];
    __shared__ int s_lab[NG];
    __shared__ float pbx[QT][11];
    __shared__ unsigned fgm[QT];

    const float i0 = img_sz[b * 4 + 0], i1 = img_sz[b * 4 + 1];
    const float i2 = img_sz[b * 4 + 2], i3 = img_sz[b * 4 + 3];

    if (tid < NG) {
        const float4 gt = *reinterpret_cast<const float4*>(gt_boxes + (b * NG + tid) * 4);
        float GX1 = (gt.x - 0.5f * gt.z) * i0, GY1 = (gt.y - 0.5f * gt.w) * i1;
        float GX2 = (gt.x + 0.5f * gt.z) * i2, GY2 = (gt.y + 0.5f * gt.w) * i3;
        float tcx = (GX1 + GX2) * 0.5f, tcy = (GY1 + GY2) * 0.5f;
        float tw = GX2 - GX1, th = GY2 - GY1;
        float X1 = tcx - 0.5f * tw, Y1 = tcy - 0.5f * th;
        float X2 = tcx + 0.5f * tw, Y2 = tcy + 0.5f * th;
        float w_ = X2 - X1, h_ = Y2 - Y1;
        s_rx1[tid] = X1; s_ry1[tid] = Y1; s_rx2[tid] = X2; s_ry2[tid] = Y2;
        s_clx[tid] = tcx - 2.5f * w_; s_chx[tid] = tcx + 2.5f * w_;
        s_cly[tid] = tcy - 2.5f * h_; s_chy[tid] = tcy + 2.5f * h_;
        s_gx1[tid] = GX1; s_gy1[tid] = GY1; s_gx2[tid] = GX2; s_gy2[tid] = GY2;
        s_d1[tid] = GX1 / i0; s_d2[tid] = GY1 / i1; s_d3[tid] = GX2 / i2; s_d4[tid] = GY2 / i3;
        s_ga[tid] = (GX2 - GX1) * (GY2 - GY1);
        s_lab[tid] = labels[b * NG + tid];
    }
    if (tid < QT) {
        fgm[tid] = 0;
        int q = q0 + tid;
        if (q < NQ) {
            const float4 pb = *reinterpret_cast<const float4*>(pred_boxes + (size_t)(b * NQ + q) * 4);
            float x1 = (pb.x - 0.5f * pb.z) * i0, y1 = (pb.y - 0.5f * pb.w) * i1;
            float x2 = (pb.x + 0.5f * pb.z) * i2, y2 = (pb.y + 0.5f * pb.w) * i3;
            pbx[tid][0] = x1; pbx[tid][1] = y1; pbx[tid][2] = x2; pbx[tid][3] = y2;
            pbx[tid][4] = (x1 + x2) * 0.5f; pbx[tid][5] = (y1 + y2) * 0.5f;
            pbx[tid][6] = x1 / i0; pbx[tid][7] = y1 / i1; pbx[tid][8] = x2 / i2; pbx[tid][9] = y2 / i3;
            pbx[tid][10] = (x2 - x1) * (y2 - y1);
        }
    }
    __syncthreads();

    // fg: 4-way split over g per q
    {
        int ql = tid & 63, part = tid >> 6;
        if (q0 + ql < NQ) {
            float ax = pbx[ql][4], ay = pbx[ql][5];
            bool any = false;
            for (int g = part * 25; g < part * 25 + 25; ++g) {
                bool in_box = (ax > s_rx1[g]) && (ax < s_rx2[g]) && (ay > s_ry1[g]) && (ay < s_ry2[g]);
                bool in_ctr = (ax > s_clx[g]) && (ax < s_chx[g]) && (ay > s_cly[g]) && (ay < s_chy[g]);
                any = any || in_box || in_ctr;
            }
            if (any) atomicOr(&fgm[ql], 1u);
        }
    }
    __syncthreads();

    for (int e = 0; e < QT * NG / 256; ++e) {
        int idx = e * 256 + tid;
        int ql = idx / NG, g = idx - ql * NG;
        int q = q0 + ql;
        if (q < NQ) {
            float x1 = pbx[ql][0], y1 = pbx[ql][1], x2 = pbx[ql][2], y2 = pbx[ql][3];
            float ax = pbx[ql][4], ay = pbx[ql][5];
            bool in_box = (ax > s_rx1[g]) && (ax < s_rx2[g]) && (ay > s_ry1[g]) && (ay < s_ry2[g]);
            bool in_ctr = (ax > s_clx[g]) && (ax < s_chx[g]) && (ay > s_cly[g]) && (ay < s_chy[g]);
            bool in_bc = in_box && in_ctr;
            bool fgb = fgm[ql] != 0;

            float lg = logits[(size_t)(b * NQ + q) * NC + s_lab[g]];
            float p = 1.0f / (1.0f + expf(-lg));
            float neg = 0.75f * (p * p) * (-logf(1.0f - p + 1e-8f));
            float pos = 0.25f * ((1.0f - p) * (1.0f - p)) * (-logf(p + 1e-8f));
            float cc = pos - neg;

            float cb = fabsf(pbx[ql][6] - s_d1[g]);
            cb = cb + fabsf(pbx[ql][7] - s_d2[g]);
            cb = cb + fabsf(pbx[ql][8] - s_d3[g]);
            cb = cb + fabsf(pbx[ql][9] - s_d4[g]);

            float aA = pbx[ql][10];
            float GX1 = s_gx1[g], GY1 = s_gy1[g], GX2 = s_gx2[g], GY2 = s_gy2[g];
            float lx = fmaxf(x1, GX1), ly = fmaxf(y1, GY1);
            float rx = fminf(x2, GX2), ry = fminf(y2, GY2);
            float iw = fmaxf(rx - lx, 0.0f), ih = fmaxf(ry - ly, 0.0f);
            float inter = iw * ih;
            float uni = aA + s_ga[g] - inter;
            float iou = inter / uni;
            float hx1 = fminf(x1, GX1), hy1 = fminf(y1, GY1);
            float hx2 = fmaxf(x2, GX2), hy2 = fmaxf(y2, GY2);
            float hw = fmaxf(hx2 - hx1, 0.0f), hh = fmaxf(hy2 - hy1, 0.0f);
            float harea = hw * hh;
            float giou = iou - (harea - uni) / harea;

            float cost = 5.0f * cb;
            cost = cost + 2.0f * cc;
            cost = cost + 2.0f * (-giou);
            cost = cost + (in_bc ? 0.0f : 100.0f);
            cost = cost + (fgb ? 0.0f : 10000.0f);
            ct[ql][g] = cost;
        }
    }
    __syncthreads();

    float* dst = costT_all + (size_t)b * NQ * NG;
    for (int e = 0; e < QT * NG / 256; ++e) {
        int idx = e * 256 + tid;
        int g = idx >> 6, ql = idx & 63;
        int q = q0 + ql;
        if (q < NQ) dst[(size_t)g * NQ + q] = ct[ql][g];
    }
}

// =================== K2: dynk + bottom-12 (blocks 0..399) | rowargmin (blocks 400..524) ===================
__global__ __launch_bounds__(256) void init_kernel(const float* __restrict__ pred_boxes,
                                                   const float* __restrict__ gt_boxes,
                                                   const float* __restrict__ img_sz,
                                                   const float* __restrict__ costT_all,
                                                   float* __restrict__ lists,
                                                   float* __restrict__ rowamin) {
    const int tid = threadIdx.x;
    if (blockIdx.x >= 400) {
        int gtid = (blockIdx.x - 400) * 256 + tid;
        if (gtid < BATCH * NQ) {
            int b = gtid / NQ, q = gtid - b * NQ;
            const float* base = costT_all + (size_t)b * NQ * NG + q;
            float mv = base[0]; int mg = 0;
            for (int g = 1; g < NG; ++g) {
                float v = base[(size_t)g * NQ];
                if (v < mv) { mv = v; mg = g; }
            }
            rowamin[gtid] = (float)mg;
        }
        return;
    }
    // dynk + bottom-12: one wave per (b,g); branchless sorting networks
    int w = blockIdx.x * 4 + (tid >> 6);
    int lane = tid & 63;
    int b = w / NG, g = w - b * NG;

    const float i0 = img_sz[b * 4 + 0], i1 = img_sz[b * 4 + 1];
    const float i2 = img_sz[b * 4 + 2], i3 = img_sz[b * 4 + 3];
    const float4 gt = *reinterpret_cast<const float4*>(gt_boxes + (b * NG + g) * 4);
    float GX1 = (gt.x - 0.5f * gt.z) * i0, GY1 = (gt.y - 0.5f * gt.w) * i1;
    float GX2 = (gt.x + 0.5f * gt.z) * i2, GY2 = (gt.y + 0.5f * gt.w) * i3;
    float GA = (GX2 - GX1) * (GY2 - GY1);

    const float* pbox = pred_boxes + (size_t)b * NQ * 4;
    const float* col = costT_all + (size_t)b * NQ * NG + (size_t)g * NQ;

    float va[12]; int ia[12];
    float tv[5]; int ti[5];
#pragma unroll
    for (int j = 0; j < 12; ++j) { va[j] = INFINITY; ia[j] = QINF; }
#pragma unroll
    for (int j = 0; j < 5; ++j) { tv[j] = INFINITY; ti[j] = QINF; }

    for (int q = lane; q < NQ; q += 64) {
        const float4 pb = *reinterpret_cast<const float4*>(pbox + q * 4);
        float cv = col[q];
        float x1 = (pb.x - 0.5f * pb.z) * i0, y1 = (pb.y - 0.5f * pb.w) * i1;
        float x2 = (pb.x + 0.5f * pb.z) * i2, y2 = (pb.y + 0.5f * pb.w) * i3;
        float aA = (x2 - x1) * (y2 - y1);
        float lx = fmaxf(x1, GX1), ly = fmaxf(y1, GY1);
        float rx = fminf(x2, GX2), ry = fminf(y2, GY2);
        float iw = fmaxf(rx - lx, 0.0f), ih = fmaxf(ry - ly, 0.0f);
        float inter = iw * ih;
        float uni = aA + GA - inter;
        float niou = -(inter / uni);

        {
            bool ins = lexlt(niou, q, tv[4], ti[4]);
            tv[4] = ins ? niou : tv[4]; ti[4] = ins ? q : ti[4];
            CE(tv, ti, 3, 4); CE(tv, ti, 2, 3); CE(tv, ti, 1, 2); CE(tv, ti, 0, 1);
        }
        {
            bool ins = lexlt(cv, q, va[11], ia[11]);
            va[11] = ins ? cv : va[11]; ia[11] = ins ? q : ia[11];
            CE(va, ia, 10, 11); CE(va, ia, 9, 10); CE(va, ia, 8, 9); CE(va, ia, 7, 8);
            CE(va, ia, 6, 7); CE(va, ia, 5, 6); CE(va, ia, 4, 5); CE(va, ia, 3, 4);
            CE(va, ia, 2, 3); CE(va, ia, 1, 2); CE(va, ia, 0, 1);
        }
    }

#pragma unroll
    for (int off = 1; off < 64; off <<= 1) {
        float bv[12]; int bi[12];
#pragma unroll
        for (int j = 0; j < 12; ++j) { bv[j] = __shfl_xor(va[j], off, 64); bi[j] = __shfl_xor(ia[j], off, 64); }
        float mv[16]; int mi[16];
#pragma unroll
        for (int j = 0; j < 4; ++j) { mv[j] = va[j]; mi[j] = ia[j]; }
#pragma unroll
        for (int j = 4; j < 12; ++j) {
            bool t = lexlt(bv[15 - j], bi[15 - j], va[j], ia[j]);
            mv[j] = t ? bv[15 - j] : va[j]; mi[j] = t ? bi[15 - j] : ia[j];
        }
#pragma unroll
        for (int j = 12; j < 16; ++j) { mv[j] = bv[15 - j]; mi[j] = bi[15 - j]; }
#pragma unroll
        for (int d = 8; d >= 1; d >>= 1) {
#pragma unroll
            for (int i = 0; i < 16; ++i) {
                if ((i & d) == 0) CE(mv, mi, i, (i | d));
            }
        }
#pragma unroll
        for (int j = 0; j < 12; ++j) { va[j] = mv[j]; ia[j] = mi[j]; }
    }

#pragma unroll
    for (int off = 1; off < 64; off <<= 1) {
        float bv[5]; int bi[5];
#pragma unroll
        for (int j = 0; j < 5; ++j) { bv[j] = __shfl_xor(tv[j], off, 64); bi[j] = __shfl_xor(ti[j], off, 64); }
        float mv[8]; int mi[8];
#pragma unroll
        for (int j = 0; j < 3; ++j) { mv[j] = tv[j]; mi[j] = ti[j]; }
#pragma unroll
        for (int j = 3; j < 5; ++j) {
            bool t = lexlt(bv[7 - j], bi[7 - j], tv[j], ti[j]);
            mv[j] = t ? bv[7 - j] : tv[j]; mi[j] = t ? bi[7 - j] : ti[j];
        }
#pragma unroll
        for (int j = 5; j < 8; ++j) { mv[j] = bv[7 - j]; mi[j] = bi[7 - j]; }
#pragma unroll
        for (int d = 4; d >= 1; d >>= 1) {
#pragma unroll
            for (int i = 0; i < 8; ++i) {
                if ((i & d) == 0) CE(mv, mi, i, (i | d));
            }
        }
#pragma unroll
        for (int j = 0; j < 5; ++j) { tv[j] = mv[j]; ti[j] = mi[j]; }
    }

    if (lane == 0) {
        float s = -((((tv[0] + tv[1]) + tv[2]) + tv[3]) + tv[4]);
        int k = (int)s;
        if (k < 1) k = 1;
        float* o = lists + (size_t)w * LSTRIDE;
        o[0] = (float)k;
        o[1] = (float)ia[0]; o[2] = (float)ia[1]; o[3] = (float)ia[2]; o[4] = (float)ia[3];
        o[5] = (float)ia[4]; o[6] = (float)ia[5]; o[7] = (float)ia[6]; o[8] = (float)ia[7];
        o[9] = (float)ia[8]; o[10] = (float)ia[9]; o[11] = (float)ia[10]; o[12] = (float)ia[11];
    }
}

// =================== K3: per-batch dynamic-k matching (incremental loop) ===================
__global__ __launch_bounds__(K3_BS) void match_kernel(const float* __restrict__ lists,
                                                      float* __restrict__ out) {
    const int b = blockIdx.x;
    const int tid = threadIdx.x;
    const int wave = tid >> 6;
    const int lane = tid & 63;

    __shared__ uint32_t Msh[NQ][4];        // 32 KB
    __shared__ float crow[MAXC][NG + 1];   // 38.8 KB padded
    __shared__ int m_it[NQ];               // 8 KB: -1 conf0, QINF never matched, else first-bit iter
    __shared__ int16_t cidx[NQ];           // 4 KB  (-1 none, >=0 cached conf0, -2 uncached conf0)
    __shared__ int candq[NG][NCAND];       // 4.8 KB
    __shared__ int crowq[MAXC];
    __shared__ int colcnt[NG];
    __shared__ int needscan[NG];
    __shared__ int touched[128];
    __shared__ int nconf0, nscan, ntq, persist;

    float* costT = out + OFF_M + (size_t)b * NQ * NG;
    float* selOut = out + OFF_SEL + b * NQ;
    float* gtiOut = out + OFF_GTI + b * NQ;
    const float* rowamin_b = out + OFF_GTI + b * NQ;
    float* mqOut = out + OFF_MQ + b * NG;

    if (tid == 0) { nconf0 = 0; nscan = 0; ntq = 0; persist = 0; }
    for (int q = tid; q < NQ; q += K3_BS) {
        Msh[q][0] = 0; Msh[q][1] = 0; Msh[q][2] = 0; Msh[q][3] = 0;
        cidx[q] = -1; m_it[q] = QINF;
    }
    __syncthreads();

    // build M + colcnt + candidate lists
    if (tid < NG) {
        const float* o = lists + (size_t)(b * NG + tid) * LSTRIDE;
        int k = (int)o[0];
        int word = tid >> 5;
        uint32_t bit = 1u << (tid & 31);
        for (int j = 0; j < NCAND; ++j) candq[tid][j] = (int)o[1 + j];
        for (int j = 0; j < 5; ++j)
            if (j < k) atomicOr(&Msh[candq[tid][j]][word], bit);
        colcnt[tid] = k;
    }
    __syncthreads();

    // conflict0 rows -> onehot(precomputed row argmin); m_it = -1 for conf0
    for (int q = tid; q < NQ; q += K3_BS) {
        uint4 m = *reinterpret_cast<const uint4*>(&Msh[q][0]);
        int pc = __popc(m.x) + __popc(m.y) + __popc(m.z) + __popc(m.w);
        if (pc > 1) {
            int slot = atomicAdd(&nconf0, 1);
            int c = (slot < MAXC) ? slot : -1;
            cidx[q] = (c >= 0) ? (int16_t)c : (int16_t)-2;
            m_it[q] = -1;
            if (c >= 0) crowq[c] = q;
            int mg = (int)rowamin_b[q];
            uint32_t words[4] = {m.x, m.y, m.z, m.w};
            for (int w = 0; w < 4; ++w) {
                uint32_t word = words[w];
                while (word) {
                    int bp = __ffs(word) - 1;
                    word &= word - 1;
                    atomicSub(&colcnt[w * 32 + bp], 1);
                }
                Msh[q][w] = 0;
            }
            Msh[q][mg >> 5] = 1u << (mg & 31);
            atomicAdd(&colcnt[mg], 1);
        } else if (pc == 1) {
            m_it[q] = -1;  // matched at entry of it 0 and forever (single-bit init rows)
        }
    }
    __syncthreads();

    const int ncached = (nconf0 < MAXC) ? nconf0 : MAXC;
    const bool hasOvf = nconf0 > MAXC;
    for (int i = tid; i < ncached * NG; i += K3_BS) {
        int c = i / NG, g = i - c * NG;
        crow[c][g] = costT[(size_t)g * NQ + crowq[c]];
    }
    __syncthreads();

    int unm = __syncthreads_or(tid < NG && colcnt[tid] == 0);
    int L = 0;

    // ---------------- while loop (incremental) ----------------
    for (int it = 0; it < MAX_ITERS; ++it) {
        if (!unm) break;
        L = it + 1;

        // P1b: +1e5 on all cached conf0 rows (they are matched at every entry)
        for (int i = tid; i < ncached * NG; i += K3_BS) {
            int c = i / NG, g = i - c * NG;
            crow[c][g] += 100000.0f;
        }
        // P2a: candidate fast path — first bottom-12 candidate with n_q==0 (m_it>=it)
        if (tid < NG && colcnt[tid] == 0) {
            int g = tid;
            int win = -1;
            for (int j = 0; j < NCAND; ++j) {
                int qi = candq[g][j];
                if (m_it[qi] >= it) { win = qi; break; }
            }
            if (win >= 0) {
                atomicOr(&Msh[win][g >> 5], 1u << (g & 31));
                atomicMin(&m_it[win], it);
                colcnt[g] = 1;
                touched[atomicAdd(&ntq, 1)] = win;
            } else {
                needscan[atomicAdd(&nscan, 1)] = g;
            }
        }
        __syncthreads();  // B2

        int ns = nscan;
        if (ns > 0) {
            for (int s = wave; s < ns; s += NW3) {
                int g = needscan[s];
                const float* col = costT + (size_t)g * NQ;
                float mv = INFINITY; int mi = QINF;
                for (int q = lane; q < NQ; q += 64) {
                    if (m_it[q] >= it) {
                        float v = col[q];
                        if (v < mv || (v == mv && q < mi)) { mv = v; mi = q; }
                    }
                }
                for (int off = 1; off < 64; off <<= 1) {
                    float ov = __shfl_xor(mv, off); int oi = __shfl_xor(mi, off);
                    if (ov < mv || (ov == mv && oi < mi)) { mv = ov; mi = oi; }
                }
                if (mi == QINF) {  // every row penalized -> exact replay
                    for (int q = lane; q < NQ; q += 64) {
                        int nq = it - m_it[q]; if (nq < 0) nq = 0;
                        float v = fmut(col[q], nq);
                        if (v < mv || (v == mv && q < mi)) { mv = v; mi = q; }
                    }
                    for (int off = 1; off < 64; off <<= 1) {
                        float ov = __shfl_xor(mv, off); int oi = __shfl_xor(mi, off);
                        if (ov < mv || (ov == mv && oi < mi)) { mv = ov; mi = oi; }
                    }
                }
                if (lane == 0) {
                    atomicOr(&Msh[mi][g >> 5], 1u << (g & 31));
                    atomicMin(&m_it[mi], it);
                    colcnt[g] = 1;
                    touched[atomicAdd(&ntq, 1)] = mi;
                }
            }
            __syncthreads();  // B2b (ns uniform)
        }

        // conflict check on touched rows only (+ persistent non-conf0 conflicts)
        int myconf = (tid == 0 && persist) ? 1 : 0;
        int nt = ntq;
        for (int s = tid; s < nt; s += K3_BS) {
            int q = touched[s];
            uint4 m = *reinterpret_cast<const uint4*>(&Msh[q][0]);
            int pc = __popc(m.x) + __popc(m.y) + __popc(m.z) + __popc(m.w);
            if (pc > 1) {
                myconf = 1;
                if (cidx[q] == -1) persist = 1;  // non-conf0 multi-bit row persists forever
            }
        }
        int hc = __syncthreads_or(myconf);
        if (!hc) break;  // all columns matched, no reset -> reference loop exits too

        if (tid == 0) { ntq = 0; nscan = 0; }
        // P4: reset ALL conflict0 rows to onehot(argmin of current mutated row)
        for (int c = tid; c < ncached; c += K3_BS) {
            int q = crowq[c];
            float mv = crow[c][0]; int mg = 0;
            for (int g = 1; g < NG; ++g) { float v = crow[c][g]; if (v < mv) { mv = v; mg = g; } }
            int keepw = mg >> 5;
            uint32_t keepb = 1u << (mg & 31);
            for (int w = 0; w < 4; ++w) {
                uint32_t word = Msh[q][w];
                uint32_t keep = (w == keepw) ? keepb : 0u;
                uint32_t toclear = word & ~keep;
                while (toclear) {
                    int bp = __ffs(toclear) - 1;
                    toclear &= toclear - 1;
                    atomicSub(&colcnt[w * 32 + bp], 1);
                }
                if (keep && !(word & keep)) atomicAdd(&colcnt[mg], 1);
                Msh[q][w] = keep;
            }
        }
        if (hasOvf) {
            for (int q = tid; q < NQ; q += K3_BS) {
                if (cidx[q] != -2) continue;
                int k = it + 1;
                float mv = fmut(costT[q], k); int mg = 0;
                for (int g = 1; g < NG; ++g) {
                    float v = fmut(costT[(size_t)g * NQ + q], k);
                    if (v < mv) { mv = v; mg = g; }
                }
                int keepw = mg >> 5;
                uint32_t keepb = 1u << (mg & 31);
                for (int w = 0; w < 4; ++w) {
                    uint32_t word = Msh[q][w];
                    uint32_t keep = (w == keepw) ? keepb : 0u;
                    uint32_t toclear = word & ~keep;
                    while (toclear) {
                        int bp = __ffs(toclear) - 1;
                        toclear &= toclear - 1;
                        atomicSub(&colcnt[w * 32 + bp], 1);
                    }
                    if (keep && !(word & keep)) atomicAdd(&colcnt[mg], 1);
                    Msh[q][w] = keep;
                }
            }
        }
        __syncthreads();  // make P4 atomics visible before cond predicate
        unm = __syncthreads_or(tid < NG && colcnt[tid] == 0);
    }

    // final n_q(q) = max(0, L - 1 - m_it[q])  (conf0 m_it=-1 -> L; never -> 0)
    // matched_qid: argmin_q of (M ? mutated cost : 1e30)
    for (int g = wave; g < NG; g += NW3) {
        int word = g >> 5;
        uint32_t bit = 1u << (g & 31);
        const float* col = costT + (size_t)g * NQ;
        float mv = INFINITY; int mi = QINF;
        for (int q = lane; q < NQ; q += 64) {
            float v = 1e30f;
            if (Msh[q][word] & bit) {
                int c = cidx[q];
                if (c >= 0) v = crow[c][g];
                else {
                    int nq = L - 1 - m_it[q]; if (nq < 0) nq = 0;
                    v = fmut(col[q], nq);
                }
            }
            if (v < mv || (v == mv && q < mi)) { mv = v; mi = q; }
        }
        for (int off = 1; off < 64; off <<= 1) {
            float ov = __shfl_xor(mv, off); int oi = __shfl_xor(mi, off);
            if (ov < mv || (ov == mv && oi < mi)) { mv = ov; mi = oi; }
        }
        if (lane == 0) mqOut[g] = (float)mi;
    }
    // selected / gt_idx
    for (int q = tid; q < NQ; q += K3_BS) {
        uint4 m = *reinterpret_cast<const uint4*>(&Msh[q][0]);
        selOut[q] = (m.x | m.y | m.z | m.w) ? 1.0f : 0.0f;
        int gi = 0;
        if (m.x) gi = __ffs(m.x) - 1;
        else if (m.y) gi = 32 + __ffs(m.y) - 1;
        else if (m.z) gi = 64 + __ffs(m.z) - 1;
        else if (m.w) gi = 96 + __ffs(m.w) - 1;
        gtiOut[q] = (float)gi;
    }
    __syncthreads();  // all costT reads done before overwrite
    for (int i = tid; i < NQ * NG; i += K3_BS) {
        int q = i / NG;
        int g = i - q * NG;
        costT[i] = (Msh[q][g >> 5] & (1u << (g & 31))) ? 1.0f : 0.0f;
    }
}

extern "C" void kernel_launch(void* const* d_in, const int* in_sizes, int n_in,
                              void* d_out, int out_size, void* d_ws, size_t ws_size,
                              hipStream_t stream) {
    const float* logits = (const float*)d_in[0];
    const float* pboxes = (const float*)d_in[1];
    const float* gboxes = (const float*)d_in[2];
    const int* labels = (const int*)d_in[3];
    const float* img = (const float*)d_in[4];
    float* out = (float*)d_out;
    float* lists = (float*)d_ws;  // BATCH*NG*13 floats = 83.2 KB

    fgcost_kernel<<<K1_BLOCKS, 256, 0, stream>>>(logits, pboxes, gboxes, labels, img, out + OFF_M);
    init_kernel<<<525, 256, 0, stream>>>(pboxes, gboxes, img, out + OFF_M, lists, out + OFF_GTI);
    match_kernel<<<BATCH, K3_BS, 0, stream>>>(lists, out);
}

// Round 8
// 137.654 us; speedup vs baseline: 1.0884x; 1.0884x over previous
//
#include <hip/hip_runtime.h>
#include <stdint.h>

#define BATCH 16
#define NQ 2000
#define NC 80
#define NG 100
#define MAX_ITERS 1000
#define MAXC 96
#define QT 64
#define TILES 32                     // ceil(2000/64)
#define K1_BLOCKS (BATCH * TILES)    // 512
#define K3_BS 1024
#define NW3 16
#define NCAND 12
#define LSTRIDE 13                   // k + 12 candidate indices
#define QINF 0x7fffffff
#define MASK_WS_OFF 98304            // byte offset of mask dump in d_ws

// output layout (floats)
#define OFF_SEL 0
#define OFF_GTI (BATCH * NQ)                 // 32000
#define OFF_MQ (2 * BATCH * NQ)              // 64000
#define OFF_M (2 * BATCH * NQ + BATCH * NG)  // 65600

// exact replay of the reference's sequential in-place +1e5 adds
__device__ __forceinline__ float fmut(float c, int k) {
    for (int i = 0; i < k; ++i) c += 100000.0f;
    return c;
}

__device__ __forceinline__ bool lexlt(float v1, int i1, float v2, int i2) {
    return (v1 < v2) | ((v1 == v2) & (i1 < i2));
}

// branchless compare-exchange ascending between slots a<b of (val,idx) arrays
#define CE(vv, ii, a, b) do { \
    bool t_ = lexlt(vv[b], ii[b], vv[a], ii[a]); \
    float lo_ = t_ ? vv[b] : vv[a]; float hi_ = t_ ? vv[a] : vv[b]; \
    int loi_ = t_ ? ii[b] : ii[a]; int hii_ = t_ ? ii[a] : ii[b]; \
    vv[a] = lo_; vv[b] = hi_; ii[a] = loi_; ii[b] = hii_; \
} while (0)

// =================== K1: fused fg + cost, tiled, transposed write ===================
__global__ __launch_bounds__(256) void fgcost_kernel(
    const float* __restrict__ logits, const float* __restrict__ pred_boxes,
    const float* __restrict__ gt_boxes, const int* __restrict__ labels,
    const float* __restrict__ img_sz, float* __restrict__ costT_all) {
    const int tid = threadIdx.x;
    const int b = blockIdx.x / TILES;
    const int tile = blockIdx.x - b * TILES;
    const int q0 = tile * QT;

    __shared__ float ct[QT][NG + 1];
    __shared__ float s_rx1[NG], s_ry1[NG], s_rx2[NG], s_ry2[NG];
    __shared__ float s_clx[NG], s_chx[NG], s_cly[NG], s_chy[NG];
    __shared__ float s_gx1[NG], s_gy1[NG], s_gx2[NG], s_gy2[NG];
    __shared__ float s_d1[NG], s_d2[NG], s_d3[NG], s_d4[NG];
    __shared__ float s_ga[NG];
    __shared__ int s_lab[NG];
    __shared__ float pbx[QT][11];
    __shared__ unsigned fgm[QT];

    const float i0 = img_sz[b * 4 + 0], i1 = img_sz[b * 4 + 1];
    const float i2 = img_sz[b * 4 + 2], i3 = img_sz[b * 4 + 3];

    if (tid < NG) {
        const float4 gt = *reinterpret_cast<const float4*>(gt_boxes + (b * NG + tid) * 4);
        float GX1 = (gt.x - 0.5f * gt.z) * i0, GY1 = (gt.y - 0.5f * gt.w) * i1;
        float GX2 = (gt.x + 0.5f * gt.z) * i2, GY2 = (gt.y + 0.5f * gt.w) * i3;
        float tcx = (GX1 + GX2) * 0.5f, tcy = (GY1 + GY2) * 0.5f;
        float tw = GX2 - GX1, th = GY2 - GY1;
        float X1 = tcx - 0.5f * tw, Y1 = tcy - 0.5f * th;
        float X2 = tcx + 0.5f * tw, Y2 = tcy + 0.5f * th;
        float w_ = X2 - X1, h_ = Y2 - Y1;
        s_rx1[tid] = X1; s_ry1[tid] = Y1; s_rx2[tid] = X2; s_ry2[tid] = Y2;
        s_clx[tid] = tcx - 2.5f * w_; s_chx[tid] = tcx + 2.5f * w_;
        s_cly[tid] = tcy - 2.5f * h_; s_chy[tid] = tcy + 2.5f * h_;
        s_gx1[tid] = GX1; s_gy1[tid] = GY1; s_gx2[tid] = GX2; s_gy2[tid] = GY2;
        s_d1[tid] = GX1 / i0; s_d2[tid] = GY1 / i1; s_d3[tid] = GX2 / i2; s_d4[tid] = GY2 / i3;
        s_ga[tid] = (GX2 - GX1) * (GY2 - GY1);
        s_lab[tid] = labels[b * NG + tid];
    }
    if (tid < QT) {
        fgm[tid] = 0;
        int q = q0 + tid;
        if (q < NQ) {
            const float4 pb = *reinterpret_cast<const float4*>(pred_boxes + (size_t)(b * NQ + q) * 4);
            float x1 = (pb.x - 0.5f * pb.z) * i0, y1 = (pb.y - 0.5f * pb.w) * i1;
            float x2 = (pb.x + 0.5f * pb.z) * i2, y2 = (pb.y + 0.5f * pb.w) * i3;
            pbx[tid][0] = x1; pbx[tid][1] = y1; pbx[tid][2] = x2; pbx[tid][3] = y2;
            pbx[tid][4] = (x1 + x2) * 0.5f; pbx[tid][5] = (y1 + y2) * 0.5f;
            pbx[tid][6] = x1 / i0; pbx[tid][7] = y1 / i1; pbx[tid][8] = x2 / i2; pbx[tid][9] = y2 / i3;
            pbx[tid][10] = (x2 - x1) * (y2 - y1);
        }
    }
    __syncthreads();

    // fg: 4-way split over g per q
    {
        int ql = tid & 63, part = tid >> 6;
        if (q0 + ql < NQ) {
            float ax = pbx[ql][4], ay = pbx[ql][5];
            bool any = false;
            for (int g = part * 25; g < part * 25 + 25; ++g) {
                bool in_box = (ax > s_rx1[g]) && (ax < s_rx2[g]) && (ay > s_ry1[g]) && (ay < s_ry2[g]);
                bool in_ctr = (ax > s_clx[g]) && (ax < s_chx[g]) && (ay > s_cly[g]) && (ay < s_chy[g]);
                any = any || in_box || in_ctr;
            }
            if (any) atomicOr(&fgm[ql], 1u);
        }
    }
    __syncthreads();

    for (int e = 0; e < QT * NG / 256; ++e) {
        int idx = e * 256 + tid;
        int ql = idx / NG, g = idx - ql * NG;
        int q = q0 + ql;
        if (q < NQ) {
            float x1 = pbx[ql][0], y1 = pbx[ql][1], x2 = pbx[ql][2], y2 = pbx[ql][3];
            float ax = pbx[ql][4], ay = pbx[ql][5];
            bool in_box = (ax > s_rx1[g]) && (ax < s_rx2[g]) && (ay > s_ry1[g]) && (ay < s_ry2[g]);
            bool in_ctr = (ax > s_clx[g]) && (ax < s_chx[g]) && (ay > s_cly[g]) && (ay < s_chy[g]);
            bool in_bc = in_box && in_ctr;
            bool fgb = fgm[ql] != 0;

            float lg = logits[(size_t)(b * NQ + q) * NC + s_lab[g]];
            float p = 1.0f / (1.0f + expf(-lg));
            float neg = 0.75f * (p * p) * (-logf(1.0f - p + 1e-8f));
            float pos = 0.25f * ((1.0f - p) * (1.0f - p)) * (-logf(p + 1e-8f));
            float cc = pos - neg;

            float cb = fabsf(pbx[ql][6] - s_d1[g]);
            cb = cb + fabsf(pbx[ql][7] - s_d2[g]);
            cb = cb + fabsf(pbx[ql][8] - s_d3[g]);
            cb = cb + fabsf(pbx[ql][9] - s_d4[g]);

            float aA = pbx[ql][10];
            float GX1 = s_gx1[g], GY1 = s_gy1[g], GX2 = s_gx2[g], GY2 = s_gy2[g];
            float lx = fmaxf(x1, GX1), ly = fmaxf(y1, GY1);
            float rx = fminf(x2, GX2), ry = fminf(y2, GY2);
            float iw = fmaxf(rx - lx, 0.0f), ih = fmaxf(ry - ly, 0.0f);
            float inter = iw * ih;
            float uni = aA + s_ga[g] - inter;
            float iou = inter / uni;
            float hx1 = fminf(x1, GX1), hy1 = fminf(y1, GY1);
            float hx2 = fmaxf(x2, GX2), hy2 = fmaxf(y2, GY2);
            float hw = fmaxf(hx2 - hx1, 0.0f), hh = fmaxf(hy2 - hy1, 0.0f);
            float harea = hw * hh;
            float giou = iou - (harea - uni) / harea;

            float cost = 5.0f * cb;
            cost = cost + 2.0f * cc;
            cost = cost + 2.0f * (-giou);
            cost = cost + (in_bc ? 0.0f : 100.0f);
            cost = cost + (fgb ? 0.0f : 10000.0f);
            ct[ql][g] = cost;
        }
    }
    __syncthreads();

    float* dst = costT_all + (size_t)b * NQ * NG;
    for (int e = 0; e < QT * NG / 256; ++e) {
        int idx = e * 256 + tid;
        int g = idx >> 6, ql = idx & 63;
        int q = q0 + ql;
        if (q < NQ) dst[(size_t)g * NQ + q] = ct[ql][g];
    }
}

// =================== K2: dynk + bottom-12 (blocks 0..399) | rowargmin (blocks 400..524) ===================
__global__ __launch_bounds__(256) void init_kernel(const float* __restrict__ pred_boxes,
                                                   const float* __restrict__ gt_boxes,
                                                   const float* __restrict__ img_sz,
                                                   const float* __restrict__ costT_all,
                                                   float* __restrict__ lists,
                                                   float* __restrict__ rowamin) {
    const int tid = threadIdx.x;
    if (blockIdx.x >= 400) {
        int gtid = (blockIdx.x - 400) * 256 + tid;
        if (gtid < BATCH * NQ) {
            int b = gtid / NQ, q = gtid - b * NQ;
            const float* base = costT_all + (size_t)b * NQ * NG + q;
            float mv = base[0]; int mg = 0;
            for (int g = 1; g < NG; ++g) {
                float v = base[(size_t)g * NQ];
                if (v < mv) { mv = v; mg = g; }
            }
            rowamin[gtid] = (float)mg;
        }
        return;
    }
    // dynk + bottom-12: one wave per (b,g); branchless sorting networks
    int w = blockIdx.x * 4 + (tid >> 6);
    int lane = tid & 63;
    int b = w / NG, g = w - b * NG;

    const float i0 = img_sz[b * 4 + 0], i1 = img_sz[b * 4 + 1];
    const float i2 = img_sz[b * 4 + 2], i3 = img_sz[b * 4 + 3];
    const float4 gt = *reinterpret_cast<const float4*>(gt_boxes + (b * NG + g) * 4);
    float GX1 = (gt.x - 0.5f * gt.z) * i0, GY1 = (gt.y - 0.5f * gt.w) * i1;
    float GX2 = (gt.x + 0.5f * gt.z) * i2, GY2 = (gt.y + 0.5f * gt.w) * i3;
    float GA = (GX2 - GX1) * (GY2 - GY1);

    const float* pbox = pred_boxes + (size_t)b * NQ * 4;
    const float* col = costT_all + (size_t)b * NQ * NG + (size_t)g * NQ;

    float va[12]; int ia[12];
    float tv[5]; int ti[5];
#pragma unroll
    for (int j = 0; j < 12; ++j) { va[j] = INFINITY; ia[j] = QINF; }
#pragma unroll
    for (int j = 0; j < 5; ++j) { tv[j] = INFINITY; ti[j] = QINF; }

    for (int q = lane; q < NQ; q += 64) {
        const float4 pb = *reinterpret_cast<const float4*>(pbox + q * 4);
        float cv = col[q];
        float x1 = (pb.x - 0.5f * pb.z) * i0, y1 = (pb.y - 0.5f * pb.w) * i1;
        float x2 = (pb.x + 0.5f * pb.z) * i2, y2 = (pb.y + 0.5f * pb.w) * i3;
        float aA = (x2 - x1) * (y2 - y1);
        float lx = fmaxf(x1, GX1), ly = fmaxf(y1, GY1);
        float rx = fminf(x2, GX2), ry = fminf(y2, GY2);
        float iw = fmaxf(rx - lx, 0.0f), ih = fmaxf(ry - ly, 0.0f);
        float inter = iw * ih;
        float uni = aA + GA - inter;
        float niou = -(inter / uni);

        {
            bool ins = lexlt(niou, q, tv[4], ti[4]);
            tv[4] = ins ? niou : tv[4]; ti[4] = ins ? q : ti[4];
            CE(tv, ti, 3, 4); CE(tv, ti, 2, 3); CE(tv, ti, 1, 2); CE(tv, ti, 0, 1);
        }
        {
            bool ins = lexlt(cv, q, va[11], ia[11]);
            va[11] = ins ? cv : va[11]; ia[11] = ins ? q : ia[11];
            CE(va, ia, 10, 11); CE(va, ia, 9, 10); CE(va, ia, 8, 9); CE(va, ia, 7, 8);
            CE(va, ia, 6, 7); CE(va, ia, 5, 6); CE(va, ia, 4, 5); CE(va, ia, 3, 4);
            CE(va, ia, 2, 3); CE(va, ia, 1, 2); CE(va, ia, 0, 1);
        }
    }

#pragma unroll
    for (int off = 1; off < 64; off <<= 1) {
        float bv[12]; int bi[12];
#pragma unroll
        for (int j = 0; j < 12; ++j) { bv[j] = __shfl_xor(va[j], off, 64); bi[j] = __shfl_xor(ia[j], off, 64); }
        float mv[16]; int mi[16];
#pragma unroll
        for (int j = 0; j < 4; ++j) { mv[j] = va[j]; mi[j] = ia[j]; }
#pragma unroll
        for (int j = 4; j < 12; ++j) {
            bool t = lexlt(bv[15 - j], bi[15 - j], va[j], ia[j]);
            mv[j] = t ? bv[15 - j] : va[j]; mi[j] = t ? bi[15 - j] : ia[j];
        }
#pragma unroll
        for (int j = 12; j < 16; ++j) { mv[j] = bv[15 - j]; mi[j] = bi[15 - j]; }
#pragma unroll
        for (int d = 8; d >= 1; d >>= 1) {
#pragma unroll
            for (int i = 0; i < 16; ++i) {
                if ((i & d) == 0) CE(mv, mi, i, (i | d));
            }
        }
#pragma unroll
        for (int j = 0; j < 12; ++j) { va[j] = mv[j]; ia[j] = mi[j]; }
    }

#pragma unroll
    for (int off = 1; off < 64; off <<= 1) {
        float bv[5]; int bi[5];
#pragma unroll
        for (int j = 0; j < 5; ++j) { bv[j] = __shfl_xor(tv[j], off, 64); bi[j] = __shfl_xor(ti[j], off, 64); }
        float mv[8]; int mi[8];
#pragma unroll
        for (int j = 0; j < 3; ++j) { mv[j] = tv[j]; mi[j] = ti[j]; }
#pragma unroll
        for (int j = 3; j < 5; ++j) {
            bool t = lexlt(bv[7 - j], bi[7 - j], tv[j], ti[j]);
            mv[j] = t ? bv[7 - j] : tv[j]; mi[j] = t ? bi[7 - j] : ti[j];
        }
#pragma unroll
        for (int j = 5; j < 8; ++j) { mv[j] = bv[7 - j]; mi[j] = bi[7 - j]; }
#pragma unroll
        for (int d = 4; d >= 1; d >>= 1) {
#pragma unroll
            for (int i = 0; i < 8; ++i) {
                if ((i & d) == 0) CE(mv, mi, i, (i | d));
            }
        }
#pragma unroll
        for (int j = 0; j < 5; ++j) { tv[j] = mv[j]; ti[j] = mi[j]; }
    }

    if (lane == 0) {
        float s = -((((tv[0] + tv[1]) + tv[2]) + tv[3]) + tv[4]);
        int k = (int)s;
        if (k < 1) k = 1;
        float* o = lists + (size_t)w * LSTRIDE;
        o[0] = (float)k;
        o[1] = (float)ia[0]; o[2] = (float)ia[1]; o[3] = (float)ia[2]; o[4] = (float)ia[3];
        o[5] = (float)ia[4]; o[6] = (float)ia[5]; o[7] = (float)ia[6]; o[8] = (float)ia[7];
        o[9] = (float)ia[8]; o[10] = (float)ia[9]; o[11] = (float)ia[10]; o[12] = (float)ia[11];
    }
}

// =================== K3: per-batch dynamic-k matching (incremental loop) ===================
__global__ __launch_bounds__(K3_BS) void match_kernel(const float* __restrict__ lists,
                                                      uint32_t* __restrict__ maskDump,
                                                      int useDump,
                                                      float* __restrict__ out) {
    const int b = blockIdx.x;
    const int tid = threadIdx.x;
    const int wave = tid >> 6;
    const int lane = tid & 63;

    __shared__ uint32_t Msh[NQ][4];        // 32 KB
    __shared__ float crow[MAXC][NG + 1];   // 38.8 KB padded
    __shared__ int m_it[NQ];               // 8 KB: -1 conf0/init-matched, QINF never, else first-bit iter
    __shared__ int16_t cidx[NQ];           // 4 KB  (-1 none, >=0 cached conf0, -2 uncached conf0)
    __shared__ int candq[NG][NCAND];       // 4.8 KB
    __shared__ int crowq[MAXC];
    __shared__ int colcnt[NG];
    __shared__ int needscan[NG];
    __shared__ int touched[128];
    __shared__ int nconf0, nscan, ntq, persist;

    float* costT = out + OFF_M + (size_t)b * NQ * NG;
    float* selOut = out + OFF_SEL + b * NQ;
    float* gtiOut = out + OFF_GTI + b * NQ;
    const float* rowamin_b = out + OFF_GTI + b * NQ;
    float* mqOut = out + OFF_MQ + b * NG;

    if (tid == 0) { nconf0 = 0; nscan = 0; ntq = 0; persist = 0; }
    for (int q = tid; q < NQ; q += K3_BS) {
        Msh[q][0] = 0; Msh[q][1] = 0; Msh[q][2] = 0; Msh[q][3] = 0;
        cidx[q] = -1; m_it[q] = QINF;
    }
    __syncthreads();

    // build M + colcnt + candidate lists
    if (tid < NG) {
        const float* o = lists + (size_t)(b * NG + tid) * LSTRIDE;
        int k = (int)o[0];
        int word = tid >> 5;
        uint32_t bit = 1u << (tid & 31);
        for (int j = 0; j < NCAND; ++j) candq[tid][j] = (int)o[1 + j];
        for (int j = 0; j < 5; ++j)
            if (j < k) atomicOr(&Msh[candq[tid][j]][word], bit);
        colcnt[tid] = k;
    }
    __syncthreads();

    // conflict0 rows -> onehot(precomputed row argmin); m_it = -1 for conf0
    for (int q = tid; q < NQ; q += K3_BS) {
        uint4 m = *reinterpret_cast<const uint4*>(&Msh[q][0]);
        int pc = __popc(m.x) + __popc(m.y) + __popc(m.z) + __popc(m.w);
        if (pc > 1) {
            int slot = atomicAdd(&nconf0, 1);
            int c = (slot < MAXC) ? slot : -1;
            cidx[q] = (c >= 0) ? (int16_t)c : (int16_t)-2;
            m_it[q] = -1;
            if (c >= 0) crowq[c] = q;
            int mg = (int)rowamin_b[q];
            uint32_t words[4] = {m.x, m.y, m.z, m.w};
            for (int w = 0; w < 4; ++w) {
                uint32_t word = words[w];
                while (word) {
                    int bp = __ffs(word) - 1;
                    word &= word - 1;
                    atomicSub(&colcnt[w * 32 + bp], 1);
                }
                Msh[q][w] = 0;
            }
            Msh[q][mg >> 5] = 1u << (mg & 31);
            atomicAdd(&colcnt[mg], 1);
        } else if (pc == 1) {
            m_it[q] = -1;  // matched at entry of it 0 and forever (single-bit init rows)
        }
    }
    __syncthreads();

    const int ncached = (nconf0 < MAXC) ? nconf0 : MAXC;
    const bool hasOvf = nconf0 > MAXC;
    for (int i = tid; i < ncached * NG; i += K3_BS) {
        int c = i / NG, g = i - c * NG;
        crow[c][g] = costT[(size_t)g * NQ + crowq[c]];
    }
    __syncthreads();

    int unm = __syncthreads_or(tid < NG && colcnt[tid] == 0);
    int L = 0;

    // ---------------- while loop (incremental) ----------------
    for (int it = 0; it < MAX_ITERS; ++it) {
        if (!unm) break;
        L = it + 1;

        // P1b: +1e5 on all cached conf0 rows (they are matched at every entry)
        for (int i = tid; i < ncached * NG; i += K3_BS) {
            int c = i / NG, g = i - c * NG;
            crow[c][g] += 100000.0f;
        }
        // P2a: candidate fast path — first bottom-12 candidate with n_q==0 (m_it>=it)
        if (tid < NG && colcnt[tid] == 0) {
            int g = tid;
            int win = -1;
            for (int j = 0; j < NCAND; ++j) {
                int qi = candq[g][j];
                if (m_it[qi] >= it) { win = qi; break; }
            }
            if (win >= 0) {
                atomicOr(&Msh[win][g >> 5], 1u << (g & 31));
                atomicMin(&m_it[win], it);
                colcnt[g] = 1;
                touched[atomicAdd(&ntq, 1)] = win;
            } else {
                needscan[atomicAdd(&nscan, 1)] = g;
            }
        }
        __syncthreads();  // B2

        int ns = nscan;
        if (ns > 0) {
            for (int s = wave; s < ns; s += NW3) {
                int g = needscan[s];
                const float* col = costT + (size_t)g * NQ;
                float mv = INFINITY; int mi = QINF;
                for (int q = lane; q < NQ; q += 64) {
                    if (m_it[q] >= it) {
                        float v = col[q];
                        if (v < mv || (v == mv && q < mi)) { mv = v; mi = q; }
                    }
                }
                for (int off = 1; off < 64; off <<= 1) {
                    float ov = __shfl_xor(mv, off); int oi = __shfl_xor(mi, off);
                    if (ov < mv || (ov == mv && oi < mi)) { mv = ov; mi = oi; }
                }
                if (mi == QINF) {  // every row penalized -> exact replay
                    for (int q = lane; q < NQ; q += 64) {
                        int nq = it - m_it[q]; if (nq < 0) nq = 0;
                        float v = fmut(col[q], nq);
                        if (v < mv || (v == mv && q < mi)) { mv = v; mi = q; }
                    }
                    for (int off = 1; off < 64; off <<= 1) {
                        float ov = __shfl_xor(mv, off); int oi = __shfl_xor(mi, off);
                        if (ov < mv || (ov == mv && oi < mi)) { mv = ov; mi = oi; }
                    }
                }
                if (lane == 0) {
                    atomicOr(&Msh[mi][g >> 5], 1u << (g & 31));
                    atomicMin(&m_it[mi], it);
                    colcnt[g] = 1;
                    touched[atomicAdd(&ntq, 1)] = mi;
                }
            }
            __syncthreads();  // B2b (ns uniform)
        }

        // conflict check on touched rows only (+ persistent non-conf0 conflicts)
        int myconf = (tid == 0 && persist) ? 1 : 0;
        int nt = ntq;
        for (int s = tid; s < nt; s += K3_BS) {
            int q = touched[s];
            uint4 m = *reinterpret_cast<const uint4*>(&Msh[q][0]);
            int pc = __popc(m.x) + __popc(m.y) + __popc(m.z) + __popc(m.w);
            if (pc > 1) {
                myconf = 1;
                if (cidx[q] == -1) persist = 1;  // non-conf0 multi-bit row persists forever
            }
        }
        int hc = __syncthreads_or(myconf);
        if (!hc) break;  // all columns matched, no reset -> reference loop exits too

        if (tid == 0) { ntq = 0; nscan = 0; }
        // P4: reset ALL conflict0 rows to onehot(argmin of current mutated row)
        for (int c = tid; c < ncached; c += K3_BS) {
            int q = crowq[c];
            float mv = crow[c][0]; int mg = 0;
            for (int g = 1; g < NG; ++g) { float v = crow[c][g]; if (v < mv) { mv = v; mg = g; } }
            int keepw = mg >> 5;
            uint32_t keepb = 1u << (mg & 31);
            for (int w = 0; w < 4; ++w) {
                uint32_t word = Msh[q][w];
                uint32_t keep = (w == keepw) ? keepb : 0u;
                uint32_t toclear = word & ~keep;
                while (toclear) {
                    int bp = __ffs(toclear) - 1;
                    toclear &= toclear - 1;
                    atomicSub(&colcnt[w * 32 + bp], 1);
                }
                if (keep && !(word & keep)) atomicAdd(&colcnt[mg], 1);
                Msh[q][w] = keep;
            }
        }
        if (hasOvf) {
            for (int q = tid; q < NQ; q += K3_BS) {
                if (cidx[q] != -2) continue;
                int k = it + 1;
                float mv = fmut(costT[q], k); int mg = 0;
                for (int g = 1; g < NG; ++g) {
                    float v = fmut(costT[(size_t)g * NQ + q], k);
                    if (v < mv) { mv = v; mg = g; }
                }
                int keepw = mg >> 5;
                uint32_t keepb = 1u << (mg & 31);
                for (int w = 0; w < 4; ++w) {
                    uint32_t word = Msh[q][w];
                    uint32_t keep = (w == keepw) ? keepb : 0u;
                    uint32_t toclear = word & ~keep;
                    while (toclear) {
                        int bp = __ffs(toclear) - 1;
                        toclear &= toclear - 1;
                        atomicSub(&colcnt[w * 32 + bp], 1);
                    }
                    if (keep && !(word & keep)) atomicAdd(&colcnt[mg], 1);
                    Msh[q][w] = keep;
                }
            }
        }
        __syncthreads();  // make P4 atomics visible before cond predicate
        unm = __syncthreads_or(tid < NG && colcnt[tid] == 0);
    }

    // final n_q(q) = max(0, L - 1 - m_it[q])  (conf0 m_it=-1 -> L; never -> 0)
    // matched_qid: argmin_q of (M ? mutated cost : 1e30)
    for (int g = wave; g < NG; g += NW3) {
        int word = g >> 5;
        uint32_t bit = 1u << (g & 31);
        const float* col = costT + (size_t)g * NQ;
        float mv = INFINITY; int mi = QINF;
        for (int q = lane; q < NQ; q += 64) {
            float v = 1e30f;
            if (Msh[q][word] & bit) {
                int c = cidx[q];
                if (c >= 0) v = crow[c][g];
                else {
                    int nq = L - 1 - m_it[q]; if (nq < 0) nq = 0;
                    v = fmut(col[q], nq);
                }
            }
            if (v < mv || (v == mv && q < mi)) { mv = v; mi = q; }
        }
        for (int off = 1; off < 64; off <<= 1) {
            float ov = __shfl_xor(mv, off); int oi = __shfl_xor(mi, off);
            if (ov < mv || (ov == mv && oi < mi)) { mv = ov; mi = oi; }
        }
        if (lane == 0) mqOut[g] = (float)mi;
    }
    // selected / gt_idx
    for (int q = tid; q < NQ; q += K3_BS) {
        uint4 m = *reinterpret_cast<const uint4*>(&Msh[q][0]);
        selOut[q] = (m.x | m.y | m.z | m.w) ? 1.0f : 0.0f;
        int gi = 0;
        if (m.x) gi = __ffs(m.x) - 1;
        else if (m.y) gi = 32 + __ffs(m.y) - 1;
        else if (m.z) gi = 64 + __ffs(m.z) - 1;
        else if (m.w) gi = 96 + __ffs(m.w) - 1;
        gtiOut[q] = (float)gi;
    }

    if (useDump) {
        // dump bitmasks to ws; expand_kernel materializes M with full-grid BW
        uint4* dmp = reinterpret_cast<uint4*>(maskDump) + (size_t)b * NQ;
        for (int q = tid; q < NQ; q += K3_BS)
            dmp[q] = *reinterpret_cast<const uint4*>(&Msh[q][0]);
    } else {
        __syncthreads();  // all costT reads done before overwrite
        for (int i = tid; i < NQ * NG; i += K3_BS) {
            int q = i / NG;
            int g = i - q * NG;
            costT[i] = (Msh[q][g >> 5] & (1u << (g & 31))) ? 1.0f : 0.0f;
        }
    }
}

// =================== K4: expand bitmasks -> M floats (full-grid BW) ===================
__global__ __launch_bounds__(256) void expand_kernel(const uint32_t* __restrict__ maskDump,
                                                     float* __restrict__ outM) {
    const int blk = blockIdx.x;      // BATCH*8 blocks; 250 q-rows each
    const int b = blk >> 3, j = blk & 7;
    const int q0 = j * 250;
    __shared__ uint4 msk[250];
    const uint4* src = reinterpret_cast<const uint4*>(maskDump) + (size_t)b * NQ + q0;
    for (int i = threadIdx.x; i < 250; i += 256) msk[i] = src[i];
    __syncthreads();
    float4* dst = reinterpret_cast<float4*>(outM + (size_t)b * NQ * NG + (size_t)q0 * NG);
    // 250*100/4 = 6250 float4 per block; chunks never straddle mask words (32%4==0)
    for (int i = threadIdx.x; i < 6250; i += 256) {
        int flat = i * 4;
        int ql = flat / NG;
        int g0 = flat - ql * NG;
        uint4 m = msk[ql];
        uint32_t w = (g0 < 32) ? m.x : (g0 < 64) ? m.y : (g0 < 96) ? m.z : m.w;
        int sh = g0 & 31;
        float4 v;
        v.x = ((w >> sh) & 1) ? 1.0f : 0.0f;
        v.y = ((w >> (sh + 1)) & 1) ? 1.0f : 0.0f;
        v.z = ((w >> (sh + 2)) & 1) ? 1.0f : 0.0f;
        v.w = ((w >> (sh + 3)) & 1) ? 1.0f : 0.0f;
        dst[i] = v;
    }
}

extern "C" void kernel_launch(void* const* d_in, const int* in_sizes, int n_in,
                              void* d_out, int out_size, void* d_ws, size_t ws_size,
                              hipStream_t stream) {
    const float* logits = (const float*)d_in[0];
    const float* pboxes = (const float*)d_in[1];
    const float* gboxes = (const float*)d_in[2];
    const int* labels = (const int*)d_in[3];
    const float* img = (const float*)d_in[4];
    float* out = (float*)d_out;
    float* lists = (float*)d_ws;  // BATCH*NG*13 floats = 83.2 KB

    const size_t need = MASK_WS_OFF + (size_t)BATCH * NQ * 4 * sizeof(uint32_t);  // ~610 KB
    const int useDump = (ws_size >= need) ? 1 : 0;
    uint32_t* maskDump = (uint32_t*)((char*)d_ws + MASK_WS_OFF);

    fgcost_kernel<<<K1_BLOCKS, 256, 0, stream>>>(logits, pboxes, gboxes, labels, img, out + OFF_M);
    init_kernel<<<525, 256, 0, stream>>>(pboxes, gboxes, img, out + OFF_M, lists, out + OFF_GTI);
    match_kernel<<<BATCH, K3_BS, 0, stream>>>(lists, maskDump, useDump, out);
    if (useDump)
        expand_kernel<<<BATCH * 8, 256, 0, stream>>>(maskDump, out + OFF_M);
}

// Round 9
// 110.966 us; speedup vs baseline: 1.3501x; 1.2405x over previous
//
#include <hip/hip_runtime.h>
#include <stdint.h>

#define BATCH 16
#define NQ 2000
#define NC 80
#define NG 100
#define MAX_ITERS 1000
#define MAXC 96
#define QT 32
#define TILES 63                     // ceil(2000/32)
#define K1_BLOCKS (BATCH * TILES)    // 1008
#define K3_BS 1024
#define NW3 16
#define NCAND 8
#define LSTRIDE 9                    // k + 8 candidate indices
#define QINF 0x7fffffff
#define MASK_WS_OFF 98304            // byte offset of mask dump in d_ws

// output layout (floats)
#define OFF_SEL 0
#define OFF_GTI (BATCH * NQ)                 // 32000
#define OFF_MQ (2 * BATCH * NQ)              // 64000
#define OFF_M (2 * BATCH * NQ + BATCH * NG)  // 65600

// exact replay of the reference's sequential in-place +1e5 adds
__device__ __forceinline__ float fmut(float c, int k) {
    for (int i = 0; i < k; ++i) c += 100000.0f;
    return c;
}

__device__ __forceinline__ bool lexlt(float v1, int i1, float v2, int i2) {
    return (v1 < v2) | ((v1 == v2) & (i1 < i2));
}

// branchless compare-exchange ascending between slots a<b of (val,idx) arrays
#define CE(vv, ii, a, b) do { \
    bool t_ = lexlt(vv[b], ii[b], vv[a], ii[a]); \
    float lo_ = t_ ? vv[b] : vv[a]; float hi_ = t_ ? vv[a] : vv[b]; \
    int loi_ = t_ ? ii[b] : ii[a]; int hii_ = t_ ? ii[a] : ii[b]; \
    vv[a] = lo_; vv[b] = hi_; ii[a] = loi_; ii[b] = hii_; \
} while (0)

// branchless insert into sorted-8
#define INS8(vv, ii, val, idx) do { float v_ = (val); int i_ = (idx); \
    bool ins_ = lexlt(v_, i_, vv[7], ii[7]); \
    vv[7] = ins_ ? v_ : vv[7]; ii[7] = ins_ ? i_ : ii[7]; \
    CE(vv, ii, 6, 7); CE(vv, ii, 5, 6); CE(vv, ii, 4, 5); CE(vv, ii, 3, 4); \
    CE(vv, ii, 2, 3); CE(vv, ii, 1, 2); CE(vv, ii, 0, 1); \
} while (0)

// =================== K1: fused fg + cost + rowargmin, tiled, transposed write ===================
__global__ __launch_bounds__(256) void fgcost_kernel(
    const float* __restrict__ logits, const float* __restrict__ pred_boxes,
    const float* __restrict__ gt_boxes, const int* __restrict__ labels,
    const float* __restrict__ img_sz, float* __restrict__ costT_all,
    float* __restrict__ rowamin) {
    const int tid = threadIdx.x;
    const int b = blockIdx.x / TILES;
    const int tile = blockIdx.x - b * TILES;
    const int q0 = tile * QT;

    __shared__ float ct[QT][NG + 1];                     // 12.9 KB; pad -> conflict-free rows
    __shared__ float s_rx1[NG], s_ry1[NG], s_rx2[NG], s_ry2[NG];
    __shared__ float s_clx[NG], s_chx[NG], s_cly[NG], s_chy[NG];
    __shared__ float s_gx1[NG], s_gy1[NG], s_gx2[NG], s_gy2[NG];
    __shared__ float s_d1[NG], s_d2[NG], s_d3[NG], s_d4[NG];
    __shared__ float s_ga[NG];
    __shared__ int s_lab[NG];
    __shared__ float pbx[QT][11];
    __shared__ unsigned fgm[QT];

    const float i0 = img_sz[b * 4 + 0], i1 = img_sz[b * 4 + 1];
    const float i2 = img_sz[b * 4 + 2], i3 = img_sz[b * 4 + 3];

    if (tid < NG) {
        const float4 gt = *reinterpret_cast<const float4*>(gt_boxes + (b * NG + tid) * 4);
        float GX1 = (gt.x - 0.5f * gt.z) * i0, GY1 = (gt.y - 0.5f * gt.w) * i1;
        float GX2 = (gt.x + 0.5f * gt.z) * i2, GY2 = (gt.y + 0.5f * gt.w) * i3;
        float tcx = (GX1 + GX2) * 0.5f, tcy = (GY1 + GY2) * 0.5f;
        float tw = GX2 - GX1, th = GY2 - GY1;
        float X1 = tcx - 0.5f * tw, Y1 = tcy - 0.5f * th;
        float X2 = tcx + 0.5f * tw, Y2 = tcy + 0.5f * th;
        float w_ = X2 - X1, h_ = Y2 - Y1;
        s_rx1[tid] = X1; s_ry1[tid] = Y1; s_rx2[tid] = X2; s_ry2[tid] = Y2;
        s_clx[tid] = tcx - 2.5f * w_; s_chx[tid] = tcx + 2.5f * w_;
        s_cly[tid] = tcy - 2.5f * h_; s_chy[tid] = tcy + 2.5f * h_;
        s_gx1[tid] = GX1; s_gy1[tid] = GY1; s_gx2[tid] = GX2; s_gy2[tid] = GY2;
        s_d1[tid] = GX1 / i0; s_d2[tid] = GY1 / i1; s_d3[tid] = GX2 / i2; s_d4[tid] = GY2 / i3;
        s_ga[tid] = (GX2 - GX1) * (GY2 - GY1);
        s_lab[tid] = labels[b * NG + tid];
    }
    if (tid < QT) {
        fgm[tid] = 0;
        int q = q0 + tid;
        if (q < NQ) {
            const float4 pb = *reinterpret_cast<const float4*>(pred_boxes + (size_t)(b * NQ + q) * 4);
            float x1 = (pb.x - 0.5f * pb.z) * i0, y1 = (pb.y - 0.5f * pb.w) * i1;
            float x2 = (pb.x + 0.5f * pb.z) * i2, y2 = (pb.y + 0.5f * pb.w) * i3;
            pbx[tid][0] = x1; pbx[tid][1] = y1; pbx[tid][2] = x2; pbx[tid][3] = y2;
            pbx[tid][4] = (x1 + x2) * 0.5f; pbx[tid][5] = (y1 + y2) * 0.5f;
            pbx[tid][6] = x1 / i0; pbx[tid][7] = y1 / i1; pbx[tid][8] = x2 / i2; pbx[tid][9] = y2 / i3;
            pbx[tid][10] = (x2 - x1) * (y2 - y1);
        }
    }
    __syncthreads();

    // fg: 8-way split over g per q (8 parts x 13 g's covers 100)
    {
        int ql = tid & 31, part = tid >> 5;
        if (q0 + ql < NQ) {
            float ax = pbx[ql][4], ay = pbx[ql][5];
            int gbeg = part * 13;
            int gend = gbeg + 13 < NG ? gbeg + 13 : NG;
            bool any = false;
            for (int g = gbeg; g < gend; ++g) {
                bool in_box = (ax > s_rx1[g]) && (ax < s_rx2[g]) && (ay > s_ry1[g]) && (ay < s_ry2[g]);
                bool in_ctr = (ax > s_clx[g]) && (ax < s_chx[g]) && (ay > s_cly[g]) && (ay < s_chy[g]);
                any = any || in_box || in_ctr;
            }
            if (any) atomicOr(&fgm[ql], 1u);
        }
    }
    __syncthreads();

    for (int idx = tid; idx < QT * NG; idx += 256) {
        int ql = idx / NG, g = idx - ql * NG;
        int q = q0 + ql;
        if (q < NQ) {
            float x1 = pbx[ql][0], y1 = pbx[ql][1], x2 = pbx[ql][2], y2 = pbx[ql][3];
            float ax = pbx[ql][4], ay = pbx[ql][5];
            bool in_box = (ax > s_rx1[g]) && (ax < s_rx2[g]) && (ay > s_ry1[g]) && (ay < s_ry2[g]);
            bool in_ctr = (ax > s_clx[g]) && (ax < s_chx[g]) && (ay > s_cly[g]) && (ay < s_chy[g]);
            bool in_bc = in_box && in_ctr;
            bool fgb = fgm[ql] != 0;

            float lg = logits[(size_t)(b * NQ + q) * NC + s_lab[g]];
            float p = 1.0f / (1.0f + expf(-lg));
            float neg = 0.75f * (p * p) * (-logf(1.0f - p + 1e-8f));
            float pos = 0.25f * ((1.0f - p) * (1.0f - p)) * (-logf(p + 1e-8f));
            float cc = pos - neg;

            float cb = fabsf(pbx[ql][6] - s_d1[g]);
            cb = cb + fabsf(pbx[ql][7] - s_d2[g]);
            cb = cb + fabsf(pbx[ql][8] - s_d3[g]);
            cb = cb + fabsf(pbx[ql][9] - s_d4[g]);

            float aA = pbx[ql][10];
            float GX1 = s_gx1[g], GY1 = s_gy1[g], GX2 = s_gx2[g], GY2 = s_gy2[g];
            float lx = fmaxf(x1, GX1), ly = fmaxf(y1, GY1);
            float rx = fminf(x2, GX2), ry = fminf(y2, GY2);
            float iw = fmaxf(rx - lx, 0.0f), ih = fmaxf(ry - ly, 0.0f);
            float inter = iw * ih;
            float uni = aA + s_ga[g] - inter;
            float iou = inter / uni;
            float hx1 = fminf(x1, GX1), hy1 = fminf(y1, GY1);
            float hx2 = fmaxf(x2, GX2), hy2 = fmaxf(y2, GY2);
            float hw = fmaxf(hx2 - hx1, 0.0f), hh = fmaxf(hy2 - hy1, 0.0f);
            float harea = hw * hh;
            float giou = iou - (harea - uni) / harea;

            float cost = 5.0f * cb;
            cost = cost + 2.0f * cc;
            cost = cost + 2.0f * (-giou);
            cost = cost + (in_bc ? 0.0f : 100.0f);
            cost = cost + (fgb ? 0.0f : 10000.0f);
            ct[ql][g] = cost;
        }
    }
    __syncthreads();

    // transpose write: costT[b][g][q], q-contiguous in 32-chunks
    float* dst = costT_all + (size_t)b * NQ * NG;
    for (int idx = tid; idx < QT * NG; idx += 256) {
        int g = idx >> 5, ql = idx & 31;
        int q = q0 + ql;
        if (q < NQ) dst[(size_t)g * NQ + q] = ct[ql][g];
    }
    // rowargmin from the LDS tile (conflict-free: stride 101)
    if (tid < QT && q0 + tid < NQ) {
        float mv = ct[tid][0]; int mg = 0;
        for (int g = 1; g < NG; ++g) { float v = ct[tid][g]; if (v < mv) { mv = v; mg = g; } }
        rowamin[b * NQ + q0 + tid] = (float)mg;
    }
}

// =================== K2: taskA bottom-8 cost (blocks 0..399) | taskB dynk (blocks 400..799) ===================
__global__ __launch_bounds__(256) void init_kernel(const float* __restrict__ pred_boxes,
                                                   const float* __restrict__ gt_boxes,
                                                   const float* __restrict__ img_sz,
                                                   const float* __restrict__ costT_all,
                                                   float* __restrict__ lists) {
    const int tid = threadIdx.x;
    const int wid = tid >> 6, lane = tid & 63;

    if (blockIdx.x < 400) {
        // task A: sorted bottom-8 of (cost, q) per column; one wave per (b,g)
        int w = blockIdx.x * 4 + wid;
        int b = w / NG, g = w - b * NG;
        const float* col = costT_all + (size_t)b * NQ * NG + (size_t)g * NQ;

        float va[8]; int ia[8];
#pragma unroll
        for (int j = 0; j < 8; ++j) { va[j] = INFINITY; ia[j] = QINF; }
        for (int q = lane; q < NQ; q += 64) {
            float v = col[q];
            INS8(va, ia, v, q);
        }
#pragma unroll
        for (int off = 1; off < 64; off <<= 1) {
            float bv[8]; int bi[8];
#pragma unroll
            for (int j = 0; j < 8; ++j) { bv[j] = __shfl_xor(va[j], off, 64); bi[j] = __shfl_xor(ia[j], off, 64); }
            float mv[8]; int mi[8];
#pragma unroll
            for (int j = 0; j < 8; ++j) {
                bool t = lexlt(bv[7 - j], bi[7 - j], va[j], ia[j]);
                mv[j] = t ? bv[7 - j] : va[j]; mi[j] = t ? bi[7 - j] : ia[j];
            }
#pragma unroll
            for (int d = 4; d >= 1; d >>= 1) {
#pragma unroll
                for (int i = 0; i < 8; ++i) {
                    if ((i & d) == 0) CE(mv, mi, i, (i | d));
                }
            }
#pragma unroll
            for (int j = 0; j < 8; ++j) { va[j] = mv[j]; ia[j] = mi[j]; }
        }
        if (lane == 0) {
            float* o = lists + (size_t)w * LSTRIDE;
            o[1] = (float)ia[0]; o[2] = (float)ia[1]; o[3] = (float)ia[2]; o[4] = (float)ia[3];
            o[5] = (float)ia[4]; o[6] = (float)ia[5]; o[7] = (float)ia[6]; o[8] = (float)ia[7];
        }
        return;
    }

    // task B: top-5 IoU -> dyn_k; one wave per (b,g)
    int w = (blockIdx.x - 400) * 4 + wid;
    int b = w / NG, g = w - b * NG;

    const float i0 = img_sz[b * 4 + 0], i1 = img_sz[b * 4 + 1];
    const float i2 = img_sz[b * 4 + 2], i3 = img_sz[b * 4 + 3];
    const float4 gt = *reinterpret_cast<const float4*>(gt_boxes + (b * NG + g) * 4);
    float GX1 = (gt.x - 0.5f * gt.z) * i0, GY1 = (gt.y - 0.5f * gt.w) * i1;
    float GX2 = (gt.x + 0.5f * gt.z) * i2, GY2 = (gt.y + 0.5f * gt.w) * i3;
    float GA = (GX2 - GX1) * (GY2 - GY1);

    const float* pbox = pred_boxes + (size_t)b * NQ * 4;
    float tv[5]; int ti[5];
#pragma unroll
    for (int j = 0; j < 5; ++j) { tv[j] = INFINITY; ti[j] = QINF; }

    for (int q = lane; q < NQ; q += 64) {
        const float4 pb = *reinterpret_cast<const float4*>(pbox + q * 4);
        float x1 = (pb.x - 0.5f * pb.z) * i0, y1 = (pb.y - 0.5f * pb.w) * i1;
        float x2 = (pb.x + 0.5f * pb.z) * i2, y2 = (pb.y + 0.5f * pb.w) * i3;
        float aA = (x2 - x1) * (y2 - y1);
        float lx = fmaxf(x1, GX1), ly = fmaxf(y1, GY1);
        float rx = fminf(x2, GX2), ry = fminf(y2, GY2);
        float iw = fmaxf(rx - lx, 0.0f), ih = fmaxf(ry - ly, 0.0f);
        float inter = iw * ih;
        float uni = aA + GA - inter;
        float niou = -(inter / uni);
        bool ins = lexlt(niou, q, tv[4], ti[4]);
        tv[4] = ins ? niou : tv[4]; ti[4] = ins ? q : ti[4];
        CE(tv, ti, 3, 4); CE(tv, ti, 2, 3); CE(tv, ti, 1, 2); CE(tv, ti, 0, 1);
    }

#pragma unroll
    for (int off = 1; off < 64; off <<= 1) {
        float bv[5]; int bi[5];
#pragma unroll
        for (int j = 0; j < 5; ++j) { bv[j] = __shfl_xor(tv[j], off, 64); bi[j] = __shfl_xor(ti[j], off, 64); }
        float mv[8]; int mi[8];
#pragma unroll
        for (int j = 0; j < 3; ++j) { mv[j] = tv[j]; mi[j] = ti[j]; }
#pragma unroll
        for (int j = 3; j < 5; ++j) {
            bool t = lexlt(bv[7 - j], bi[7 - j], tv[j], ti[j]);
            mv[j] = t ? bv[7 - j] : tv[j]; mi[j] = t ? bi[7 - j] : ti[j];
        }
#pragma unroll
        for (int j = 5; j < 8; ++j) { mv[j] = bv[7 - j]; mi[j] = bi[7 - j]; }
#pragma unroll
        for (int d = 4; d >= 1; d >>= 1) {
#pragma unroll
            for (int i = 0; i < 8; ++i) {
                if ((i & d) == 0) CE(mv, mi, i, (i | d));
            }
        }
#pragma unroll
        for (int j = 0; j < 5; ++j) { tv[j] = mv[j]; ti[j] = mi[j]; }
    }

    if (lane == 0) {
        float s = -((((tv[0] + tv[1]) + tv[2]) + tv[3]) + tv[4]);
        int k = (int)s;
        if (k < 1) k = 1;
        lists[(size_t)w * LSTRIDE] = (float)k;
    }
}

// =================== K3: per-batch dynamic-k matching (incremental loop) ===================
__global__ __launch_bounds__(K3_BS) void match_kernel(const float* __restrict__ lists,
                                                      uint32_t* __restrict__ maskDump,
                                                      int useDump,
                                                      float* __restrict__ out) {
    const int b = blockIdx.x;
    const int tid = threadIdx.x;
    const int wave = tid >> 6;
    const int lane = tid & 63;

    __shared__ uint32_t Msh[NQ][4];        // 32 KB
    __shared__ float crow[MAXC][NG + 1];   // 38.8 KB padded
    __shared__ int m_it[NQ];               // 8 KB: -1 conf0/init-matched, QINF never, else first-bit iter
    __shared__ int16_t cidx[NQ];           // 4 KB  (-1 none, >=0 cached conf0, -2 uncached conf0)
    __shared__ int candq[NG][NCAND];       // 3.2 KB
    __shared__ int crowq[MAXC];
    __shared__ int colcnt[NG];
    __shared__ int needscan[NG];
    __shared__ int touched[128];
    __shared__ int nconf0, nscan, ntq, persist;

    float* costT = out + OFF_M + (size_t)b * NQ * NG;
    float* selOut = out + OFF_SEL + b * NQ;
    float* gtiOut = out + OFF_GTI + b * NQ;
    const float* rowamin_b = out + OFF_GTI + b * NQ;
    float* mqOut = out + OFF_MQ + b * NG;

    if (tid == 0) { nconf0 = 0; nscan = 0; ntq = 0; persist = 0; }
    for (int q = tid; q < NQ; q += K3_BS) {
        Msh[q][0] = 0; Msh[q][1] = 0; Msh[q][2] = 0; Msh[q][3] = 0;
        cidx[q] = -1; m_it[q] = QINF;
    }
    __syncthreads();

    // build M + colcnt + candidate lists
    if (tid < NG) {
        const float* o = lists + (size_t)(b * NG + tid) * LSTRIDE;
        int k = (int)o[0];
        int word = tid >> 5;
        uint32_t bit = 1u << (tid & 31);
        for (int j = 0; j < NCAND; ++j) candq[tid][j] = (int)o[1 + j];
        for (int j = 0; j < 5; ++j)
            if (j < k) atomicOr(&Msh[candq[tid][j]][word], bit);
        colcnt[tid] = k;
    }
    __syncthreads();

    // conflict0 rows -> onehot(precomputed row argmin); m_it = -1 for conf0
    for (int q = tid; q < NQ; q += K3_BS) {
        uint4 m = *reinterpret_cast<const uint4*>(&Msh[q][0]);
        int pc = __popc(m.x) + __popc(m.y) + __popc(m.z) + __popc(m.w);
        if (pc > 1) {
            int slot = atomicAdd(&nconf0, 1);
            int c = (slot < MAXC) ? slot : -1;
            cidx[q] = (c >= 0) ? (int16_t)c : (int16_t)-2;
            m_it[q] = -1;
            if (c >= 0) crowq[c] = q;
            int mg = (int)rowamin_b[q];
            uint32_t words[4] = {m.x, m.y, m.z, m.w};
            for (int w = 0; w < 4; ++w) {
                uint32_t word = words[w];
                while (word) {
                    int bp = __ffs(word) - 1;
                    word &= word - 1;
                    atomicSub(&colcnt[w * 32 + bp], 1);
                }
                Msh[q][w] = 0;
            }
            Msh[q][mg >> 5] = 1u << (mg & 31);
            atomicAdd(&colcnt[mg], 1);
        } else if (pc == 1) {
            m_it[q] = -1;  // matched at entry of it 0 and forever (single-bit init rows)
        }
    }
    __syncthreads();

    const int ncached = (nconf0 < MAXC) ? nconf0 : MAXC;
    const bool hasOvf = nconf0 > MAXC;
    for (int i = tid; i < ncached * NG; i += K3_BS) {
        int c = i / NG, g = i - c * NG;
        crow[c][g] = costT[(size_t)g * NQ + crowq[c]];
    }
    __syncthreads();

    int unm = __syncthreads_or(tid < NG && colcnt[tid] == 0);
    int L = 0;

    // ---------------- while loop (incremental) ----------------
    for (int it = 0; it < MAX_ITERS; ++it) {
        if (!unm) break;
        L = it + 1;

        // P1b: +1e5 on all cached conf0 rows (they are matched at every entry)
        for (int i = tid; i < ncached * NG; i += K3_BS) {
            int c = i / NG, g = i - c * NG;
            crow[c][g] += 100000.0f;
        }
        // P2a: candidate fast path — first bottom-8 candidate with n_q==0 (m_it>=it)
        if (tid < NG && colcnt[tid] == 0) {
            int g = tid;
            int win = -1;
            for (int j = 0; j < NCAND; ++j) {
                int qi = candq[g][j];
                if (m_it[qi] >= it) { win = qi; break; }
            }
            if (win >= 0) {
                atomicOr(&Msh[win][g >> 5], 1u << (g & 31));
                atomicMin(&m_it[win], it);
                colcnt[g] = 1;
                touched[atomicAdd(&ntq, 1)] = win;
            } else {
                needscan[atomicAdd(&nscan, 1)] = g;
            }
        }
        __syncthreads();  // B2

        int ns = nscan;
        if (ns > 0) {
            for (int s = wave; s < ns; s += NW3) {
                int g = needscan[s];
                const float* col = costT + (size_t)g * NQ;
                float mv = INFINITY; int mi = QINF;
                for (int q = lane; q < NQ; q += 64) {
                    if (m_it[q] >= it) {
                        float v = col[q];
                        if (v < mv || (v == mv && q < mi)) { mv = v; mi = q; }
                    }
                }
                for (int off = 1; off < 64; off <<= 1) {
                    float ov = __shfl_xor(mv, off); int oi = __shfl_xor(mi, off);
                    if (ov < mv || (ov == mv && oi < mi)) { mv = ov; mi = oi; }
                }
                if (mi == QINF) {  // every row penalized -> exact replay
                    for (int q = lane; q < NQ; q += 64) {
                        int nq = it - m_it[q]; if (nq < 0) nq = 0;
                        float v = fmut(col[q], nq);
                        if (v < mv || (v == mv && q < mi)) { mv = v; mi = q; }
                    }
                    for (int off = 1; off < 64; off <<= 1) {
                        float ov = __shfl_xor(mv, off); int oi = __shfl_xor(mi, off);
                        if (ov < mv || (ov == mv && oi < mi)) { mv = ov; mi = oi; }
                    }
                }
                if (lane == 0) {
                    atomicOr(&Msh[mi][g >> 5], 1u << (g & 31));
                    atomicMin(&m_it[mi], it);
                    colcnt[g] = 1;
                    touched[atomicAdd(&ntq, 1)] = mi;
                }
            }
            __syncthreads();  // B2b (ns uniform)
        }

        // conflict check on touched rows only (+ persistent non-conf0 conflicts)
        int myconf = (tid == 0 && persist) ? 1 : 0;
        int nt = ntq;
        for (int s = tid; s < nt; s += K3_BS) {
            int q = touched[s];
            uint4 m = *reinterpret_cast<const uint4*>(&Msh[q][0]);
            int pc = __popc(m.x) + __popc(m.y) + __popc(m.z) + __popc(m.w);
            if (pc > 1) {
                myconf = 1;
                if (cidx[q] == -1) persist = 1;  // non-conf0 multi-bit row persists forever
            }
        }
        int hc = __syncthreads_or(myconf);
        if (!hc) break;  // all columns matched, no reset -> reference loop exits too

        if (tid == 0) { ntq = 0; nscan = 0; }
        // P4: reset ALL conflict0 rows to onehot(argmin of current mutated row)
        for (int c = tid; c < ncached; c += K3_BS) {
            int q = crowq[c];
            float mv = crow[c][0]; int mg = 0;
            for (int g = 1; g < NG; ++g) { float v = crow[c][g]; if (v < mv) { mv = v; mg = g; } }
            int keepw = mg >> 5;
            uint32_t keepb = 1u << (mg & 31);
            for (int w = 0; w < 4; ++w) {
                uint32_t word = Msh[q][w];
                uint32_t keep = (w == keepw) ? keepb : 0u;
                uint32_t toclear = word & ~keep;
                while (toclear) {
                    int bp = __ffs(toclear) - 1;
                    toclear &= toclear - 1;
                    atomicSub(&colcnt[w * 32 + bp], 1);
                }
                if (keep && !(word & keep)) atomicAdd(&colcnt[mg], 1);
                Msh[q][w] = keep;
            }
        }
        if (hasOvf) {
            for (int q = tid; q < NQ; q += K3_BS) {
                if (cidx[q] != -2) continue;
                int k = it + 1;
                float mv = fmut(costT[q], k); int mg = 0;
                for (int g = 1; g < NG; ++g) {
                    float v = fmut(costT[(size_t)g * NQ + q], k);
                    if (v < mv) { mv = v; mg = g; }
                }
                int keepw = mg >> 5;
                uint32_t keepb = 1u << (mg & 31);
                for (int w = 0; w < 4; ++w) {
                    uint32_t word = Msh[q][w];
                    uint32_t keep = (w == keepw) ? keepb : 0u;
                    uint32_t toclear = word & ~keep;
                    while (toclear) {
                        int bp = __ffs(toclear) - 1;
                        toclear &= toclear - 1;
                        atomicSub(&colcnt[w * 32 + bp], 1);
                    }
                    if (keep && !(word & keep)) atomicAdd(&colcnt[mg], 1);
                    Msh[q][w] = keep;
                }
            }
        }
        __syncthreads();  // make P4 atomics visible before cond predicate
        unm = __syncthreads_or(tid < NG && colcnt[tid] == 0);
    }

    // final n_q(q) = max(0, L - 1 - m_it[q])  (conf0 m_it=-1 -> L; never -> 0)
    // matched_qid: argmin_q of (M ? mutated cost : 1e30)
    for (int g = wave; g < NG; g += NW3) {
        int word = g >> 5;
        uint32_t bit = 1u << (g & 31);
        const float* col = costT + (size_t)g * NQ;
        float mv = INFINITY; int mi = QINF;
        for (int q = lane; q < NQ; q += 64) {
            float v = 1e30f;
            if (Msh[q][word] & bit) {
                int c = cidx[q];
                if (c >= 0) v = crow[c][g];
                else {
                    int nq = L - 1 - m_it[q]; if (nq < 0) nq = 0;
                    v = fmut(col[q], nq);
                }
            }
            if (v < mv || (v == mv && q < mi)) { mv = v; mi = q; }
        }
        for (int off = 1; off < 64; off <<= 1) {
            float ov = __shfl_xor(mv, off); int oi = __shfl_xor(mi, off);
            if (ov < mv || (ov == mv && oi < mi)) { mv = ov; mi = oi; }
        }
        if (lane == 0) mqOut[g] = (float)mi;
    }
    // selected / gt_idx
    for (int q = tid; q < NQ; q += K3_BS) {
        uint4 m = *reinterpret_cast<const uint4*>(&Msh[q][0]);
        selOut[q] = (m.x | m.y | m.z | m.w) ? 1.0f : 0.0f;
        int gi = 0;
        if (m.x) gi = __ffs(m.x) - 1;
        else if (m.y) gi = 32 + __ffs(m.y) - 1;
        else if (m.z) gi = 64 + __ffs(m.z) - 1;
        else if (m.w) gi = 96 + __ffs(m.w) - 1;
        gtiOut[q] = (float)gi;
    }

    if (useDump) {
        // dump bitmasks to ws; expand_kernel materializes M with full-grid BW
        uint4* dmp = reinterpret_cast<uint4*>(maskDump) + (size_t)b * NQ;
        for (int q = tid; q < NQ; q += K3_BS)
            dmp[q] = *reinterpret_cast<const uint4*>(&Msh[q][0]);
    } else {
        __syncthreads();  // all costT reads done before overwrite
        for (int i = tid; i < NQ * NG; i += K3_BS) {
            int q = i / NG;
            int g = i - q * NG;
            costT[i] = (Msh[q][g >> 5] & (1u << (g & 31))) ? 1.0f : 0.0f;
        }
    }
}

// =================== K4: expand bitmasks -> M floats (full-grid BW) ===================
__global__ __launch_bounds__(256) void expand_kernel(const uint32_t* __restrict__ maskDump,
                                                     float* __restrict__ outM) {
    const int blk = blockIdx.x;      // BATCH*8 blocks; 250 q-rows each
    const int b = blk >> 3, j = blk & 7;
    const int q0 = j * 250;
    __shared__ uint4 msk[250];
    const uint4* src = reinterpret_cast<const uint4*>(maskDump) + (size_t)b * NQ + q0;
    for (int i = threadIdx.x; i < 250; i += 256) msk[i] = src[i];
    __syncthreads();
    float4* dst = reinterpret_cast<float4*>(outM + (size_t)b * NQ * NG + (size_t)q0 * NG);
    // 250*100/4 = 6250 float4 per block; chunks never straddle mask words (32%4==0)
    for (int i = threadIdx.x; i < 6250; i += 256) {
        int flat = i * 4;
        int ql = flat / NG;
        int g0 = flat - ql * NG;
        uint4 m = msk[ql];
        uint32_t w = (g0 < 32) ? m.x : (g0 < 64) ? m.y : (g0 < 96) ? m.z : m.w;
        int sh = g0 & 31;
        float4 v;
        v.x = ((w >> sh) & 1) ? 1.0f : 0.0f;
        v.y = ((w >> (sh + 1)) & 1) ? 1.0f : 0.0f;
        v.z = ((w >> (sh + 2)) & 1) ? 1.0f : 0.0f;
        v.w = ((w >> (sh + 3)) & 1) ? 1.0f : 0.0f;
        dst[i] = v;
    }
}

extern "C" void kernel_launch(void* const* d_in, const int* in_sizes, int n_in,
                              void* d_out, int out_size, void* d_ws, size_t ws_size,
                              hipStream_t stream) {
    const float* logits = (const float*)d_in[0];
    const float* pboxes = (const float*)d_in[1];
    const float* gboxes = (const float*)d_in[2];
    const int* labels = (const int*)d_in[3];
    const float* img = (const float*)d_in[4];
    float* out = (float*)d_out;
    float* lists = (float*)d_ws;  // BATCH*NG*9 floats = 57.6 KB

    const size_t need = MASK_WS_OFF + (size_t)BATCH * NQ * 4 * sizeof(uint32_t);  // ~610 KB
    const int useDump = (ws_size >= need) ? 1 : 0;
    uint32_t* maskDump = (uint32_t*)((char*)d_ws + MASK_WS_OFF);

    fgcost_kernel<<<K1_BLOCKS, 256, 0, stream>>>(logits, pboxes, gboxes, labels, img,
                                                 out + OFF_M, out + OFF_GTI);
    init_kernel<<<800, 256, 0, stream>>>(pboxes, gboxes, img, out + OFF_M, lists);
    match_kernel<<<BATCH, K3_BS, 0, stream>>>(lists, maskDump, useDump, out);
    if (useDump)
        expand_kernel<<<BATCH * 8, 256, 0, stream>>>(maskDump, out + OFF_M);
}